// Round 11
// baseline (698.253 us; speedup 1.0000x reference)
//
#include <hip/hip_runtime.h>

#define M_DIM 16384
#define N_DIM 4096
#define K_DIM 4096
#define NCLUST 16

#define BM 256
#define BN 128
#define BKB 128               // K-tile in BYTES per row (128 fp8 elements)
#define NT (K_DIM / BKB)      // 32 K-tiles

typedef unsigned short u16;
typedef unsigned char u8;
typedef float floatx4 __attribute__((ext_vector_type(4)));
typedef int int4v __attribute__((ext_vector_type(4)));
typedef int int8v __attribute__((ext_vector_type(8)));

typedef const unsigned int __attribute__((address_space(1))) gu32;
typedef unsigned int __attribute__((address_space(3))) lu32;

// float -> OCP e4m3fn with RNE (values are pre-scaled, |x| << 448)
__device__ __forceinline__ unsigned f2fp8(float x) {
  union { float f; unsigned u; } a; a.f = x;
  unsigned s = (a.u >> 24) & 0x80u;
  float ax = fabsf(x);
  if (ax >= 448.f) return s | 0x7Eu;
  if (ax < 0.015625f) {                       // subnormal: step 2^-9
    unsigned q = (unsigned)rintf(ax * 512.0f);
    return s | q;
  }
  unsigned u = a.u & 0x7FFFFFFFu;
  u += 0xFFFFFu + ((u >> 20) & 1u);           // RNE into 3-bit mantissa
  unsigned E = u >> 23;
  return s | (((E - 120u) << 3) & 0x78u) | ((u >> 20) & 7u);
}

// ---------------- zero scratch accumulators (colsq + s_accum) ----------------
__global__ __launch_bounds__(256) void zero_kernel(float* __restrict__ p, int n) {
  int i = blockIdx.x * 256 + threadIdx.x;
  if (i < n) p[i] = 0.f;
}

// ---------------- z row-normalize -> fp8 (x64), plus copy z -> out1 ----------------
__global__ __launch_bounds__(256) void znorm_copy_kernel(const float* __restrict__ z,
                                                         float* __restrict__ out1,
                                                         u8* __restrict__ zn) {
  const int row = blockIdx.x;
  const int t = threadIdx.x;
  const size_t base = (size_t)row * K_DIM;
  const float4* zr = (const float4*)(z + base);
  float4 v[4];
  float ss = 0.f;
#pragma unroll
  for (int i = 0; i < 4; i++) {
    v[i] = zr[t + i * 256];
    ss += v[i].x * v[i].x + v[i].y * v[i].y + v[i].z * v[i].z + v[i].w * v[i].w;
  }
#pragma unroll
  for (int m = 1; m <= 32; m <<= 1) ss += __shfl_xor(ss, m, 64);
  __shared__ float red[4];
  if ((t & 63) == 0) red[t >> 6] = ss;
  __syncthreads();
  float tot = red[0] + red[1] + red[2] + red[3];
  float sc = 64.0f / fmaxf(sqrtf(tot), 1e-8f);   // x64 scaling folded into normalize
  float4* o1 = (float4*)(out1 + base);
  unsigned* znr = (unsigned*)(zn + base);
#pragma unroll
  for (int i = 0; i < 4; i++) {
    o1[t + i * 256] = v[i];
    unsigned pk = f2fp8(v[i].x * sc) | (f2fp8(v[i].y * sc) << 8) |
                  (f2fp8(v[i].z * sc) << 16) | (f2fp8(v[i].w * sc) << 24);
    znr[t + i * 256] = pk;
  }
}

// ---------------- D column squared-norms ----------------
__global__ __launch_bounds__(256) void colsq_kernel(const float* __restrict__ D,
                                                    float* __restrict__ colsq) {
  const int col = blockIdx.x * 256 + threadIdx.x;
  const int r0 = blockIdx.y * 128;
  float ss = 0.f;
#pragma unroll 4
  for (int r = 0; r < 128; r++) {
    float d = D[(size_t)(r0 + r) * N_DIM + col];
    ss += d * d;
  }
  atomicAdd(&colsq[col], ss);
}

// ---------------- D col-normalize + transpose -> fp8 (x64) DnT[N][K] ----------------
__global__ __launch_bounds__(256) void dnt_kernel(const float* __restrict__ D,
                                                  const float* __restrict__ colsq,
                                                  u8* __restrict__ dnt) {
  __shared__ float tile[64][65];
  const int c0 = blockIdx.x * 64, r0 = blockIdx.y * 64;
  const int t = threadIdx.x;
  const int tr = t >> 4;
  const int tc = (t & 15) * 4;
#pragma unroll
  for (int i = 0; i < 4; i++) {
    int row = i * 16 + tr;
    float4 v = *(const float4*)(D + (size_t)(r0 + row) * N_DIM + c0 + tc);
    tile[row][tc + 0] = v.x; tile[row][tc + 1] = v.y;
    tile[row][tc + 2] = v.z; tile[row][tc + 3] = v.w;
  }
  __syncthreads();
#pragma unroll
  for (int i = 0; i < 4; i++) {
    int nl = i * 16 + tr;
    float sc = 64.0f / fmaxf(sqrtf(colsq[c0 + nl]), 1e-8f);
    unsigned pk = f2fp8(tile[tc + 0][nl] * sc) | (f2fp8(tile[tc + 1][nl] * sc) << 8) |
                  (f2fp8(tile[tc + 2][nl] * sc) << 16) | (f2fp8(tile[tc + 3][nl] * sc) << 24);
    *(unsigned*)(dnt + (size_t)(c0 + nl) * K_DIM + r0 + tc) = pk;
  }
}

// ---------------- GEMM: 256x128, fp8, reg-pipelined single-barrier iters ----------------
// R11: same index/swizzle math as R10 (0 conflicts, no spill), new schedule:
// per K-tile {vmcnt(6); barrier; stage kt+3 (6 loads, 3-buffer rotation);
// ds_read frags(kt+1) into NEXT reg set (16 b128); 16 MFMA on CUR set;
// lgkmcnt(0)}. Reads are serviced DURING the MFMA cluster; the end-of-iter
// lgkm drain + single barrier guarantee staging never lands on a buffer
// still being read. 3 LDS buffers (144 KB) make stage target disjoint from
// both read targets. Frag ping-pong via unroll-2 (static names).
__global__ __launch_bounds__(512, 1) void gemm_kernel(const u8* __restrict__ zn,
                                                      const u8* __restrict__ dnt,
                                                      float* __restrict__ s_accum) {
  __shared__ u8 ldsA[3 * BM * BKB];   // 3 x 32 KB  (rows: [MH0 0..127][MH1 128..255])
  __shared__ u8 ldsB[3 * BN * BKB];   // 3 x 16 KB -> 144 KB total

  const int t = threadIdx.x;
  const int w = t >> 6, l = t & 63;
  const int lr = l & 15, lk = l >> 4;

  // XCD swizzle: 2048 blocks, 256 contiguous work-ids per XCD
  const int bid = blockIdx.x;
  const int swz = (bid & 7) * 256 + (bid >> 3);
  const int bx = swz & 31, by = swz >> 5;
  const int bm = by * BM, bn = bx * BN;
  const int wm = (w >> 1) * 64, wn = (w & 1) * 64;

  // ---- staging source (perm-swizzled slot), per-lane base pointers ----
  const int y = (l & 7) ^ ((l >> 3) & 7);
  const int gs = ((y & 3) << 1) | (y >> 2);      // perm^{-1}(slot ^ row&7)
  const u8* pA1 = zn + (size_t)(bm + (w >> 2) * 64 + (w & 3) * 8 + (l >> 3)) * K_DIM + gs * 16;
  const u8* pB1 = dnt + (size_t)(bn + w * 8 + (l >> 3)) * K_DIM + gs * 16;

  // stage whole tile KT into A-buffer byte offset OA (B offset = OA>>1): 6 loads
#define STAGE(OA, KT) do { \
    const int _ob = (OA) >> 1; \
    __builtin_amdgcn_global_load_lds((gu32*)(pA1 + (size_t)(KT) * BKB), \
        (lu32*)&ldsA[(OA) + w * 1024], 16, 0, 0); \
    __builtin_amdgcn_global_load_lds((gu32*)(pA1 + (size_t)128 * K_DIM + (size_t)(KT) * BKB), \
        (lu32*)&ldsA[(OA) + 8192 + w * 1024], 16, 0, 0); \
    __builtin_amdgcn_global_load_lds((gu32*)(pA1 + (size_t)32 * K_DIM + (size_t)(KT) * BKB), \
        (lu32*)&ldsA[(OA) + 16384 + w * 1024], 16, 0, 0); \
    __builtin_amdgcn_global_load_lds((gu32*)(pA1 + (size_t)160 * K_DIM + (size_t)(KT) * BKB), \
        (lu32*)&ldsA[(OA) + 16384 + 8192 + w * 1024], 16, 0, 0); \
    __builtin_amdgcn_global_load_lds((gu32*)(pB1 + (size_t)(KT) * BKB), \
        (lu32*)&ldsB[_ob + w * 1024], 16, 0, 0); \
    __builtin_amdgcn_global_load_lds((gu32*)(pB1 + (size_t)64 * K_DIM + (size_t)(KT) * BKB), \
        (lu32*)&ldsB[_ob + 8192 + w * 1024], 16, 0, 0); \
  } while (0)

  // ---- ds_read fragment byte offsets: first slot = lk^(lr&7), pair at ^64 ----
  int aOff[4], bOff[4];
#pragma unroll
  for (int m = 0; m < 4; m++) {
    int lrow = (m >= 2 ? 128 : 0) + (w >> 1) * 32 + (m & 1) * 16 + lr;
    aOff[m] = lrow * BKB + ((lk ^ (lr & 7)) * 16);
  }
#pragma unroll
  for (int n = 0; n < 4; n++) {
    int lrow = wn + n * 16 + lr;
    bOff[n] = lrow * BKB + ((lk ^ (lr & 7)) * 16);
  }

  int8v afA[4], bfA[4], afB[4], bfB[4];
  floatx4 acc[4][4] = {};

#define LDFRAG(F, base, off) do { \
    int4v* _h = (int4v*)&(F); \
    _h[0] = *(const int4v*)((base) + (off)); \
    _h[1] = *(const int4v*)((base) + ((off) ^ 64)); \
  } while (0)

#define READF(AF, BF, OA) do { \
    const u8* _ab = ldsA + (OA); \
    const u8* _bb = ldsB + ((OA) >> 1); \
    _Pragma("unroll") \
    for (int ni = 0; ni < 4; ni++) LDFRAG(BF[ni], _bb, bOff[ni]); \
    _Pragma("unroll") \
    for (int mi = 0; mi < 4; mi++) LDFRAG(AF[mi], _ab, aOff[mi]); \
  } while (0)

#define MFMA16(AF, BF) do { \
    __builtin_amdgcn_s_setprio(1); \
    _Pragma("unroll") \
    for (int mi = 0; mi < 4; mi++) \
      _Pragma("unroll") \
      for (int ni = 0; ni < 4; ni++) \
        acc[mi][ni] = __builtin_amdgcn_mfma_scale_f32_16x16x128_f8f6f4( \
            AF[mi], BF[ni], acc[mi][ni], 0, 0, 0, 127u, 0, 127u); \
    __builtin_amdgcn_s_setprio(0); \
  } while (0)

  // one pipelined iteration: cur frags CAF/CBF (tile kt), next NAF/NBF (kt+1)
#define STEP(CAF, CBF, NAF, NBF, ORD, STG, WT) do { \
    WT; \
    __builtin_amdgcn_s_barrier(); \
    STG; \
    READF(NAF, NBF, ORD); \
    MFMA16(CAF, CBF); \
    asm volatile("s_waitcnt lgkmcnt(0)" ::: "memory"); \
  } while (0)

#define VM6 asm volatile("s_waitcnt vmcnt(6)" ::: "memory")
#define VM0 asm volatile("s_waitcnt vmcnt(0)" ::: "memory")

  // prologue: stage tiles 0,1,2 into buffers 0,1,2; read frags(0)
  STAGE(0, 0); STAGE(32768, 1); STAGE(65536, 2);
  asm volatile("s_waitcnt vmcnt(12)" ::: "memory");
  __builtin_amdgcn_s_barrier();
  READF(afA, bfA, 0);
  asm volatile("s_waitcnt lgkmcnt(0)" ::: "memory");

  int o0 = 0, o1 = 32768, o2 = 65536;   // A-offsets of buffers kt%3, (kt+1)%3, (kt+2)%3
  for (int kt = 0; kt < NT - 4; kt += 2) {
    STEP(afA, bfA, afB, bfB, o1, STAGE(o0, kt + 3), VM6);
    STEP(afB, bfB, afA, bfA, o2, STAGE(o1, kt + 4), VM6);
    int t0 = o0, t1 = o1; o0 = o2; o1 = t0; o2 = t1;   // rotate by 2
  }
  // epilogue iterations (kt = NT-4 .. NT-1), cur set = A at entry
  STEP(afA, bfA, afB, bfB, o1, STAGE(o0, NT - 1), VM6);   // kt = 28, stage tile 31
  STEP(afB, bfB, afA, bfA, o2, ((void)0), VM6);           // kt = 29, read tile 30
  STEP(afA, bfA, afB, bfB, o0, ((void)0), VM0);           // kt = 30, read tile 31
  MFMA16(afB, bfB);                                       // kt = 31

#undef STEP
#undef VM6
#undef VM0
#undef MFMA16
#undef READF
#undef LDFRAG
#undef STAGE

  // ---- epilogue: per-row square-sum over this wave's 64 cols; 2 N-halves
  // reduce via LDS; one atomicAdd per row into the block's cluster.
  __syncthreads();
  float* red = (float*)ldsA;    // [256 rows][2 wave-cols]
#pragma unroll
  for (int m = 0; m < 4; m++) {
#pragma unroll
    for (int r = 0; r < 4; r++) {
      float v = 0.f;
#pragma unroll
      for (int n = 0; n < 4; n++) { float x = acc[m][n][r]; v += x * x; }
      v += __shfl_xor(v, 1, 64);
      v += __shfl_xor(v, 2, 64);
      v += __shfl_xor(v, 4, 64);
      v += __shfl_xor(v, 8, 64);
      if (lr == 0) {
        int lrow = wm + m * 16 + lk * 4 + r;   // 0..255
        red[lrow * 2 + (w & 1)] = v;
      }
    }
  }
  __syncthreads();
  if (t < 256) {
    float s = red[t * 2 + 0] + red[t * 2 + 1];
    atomicAdd(&s_accum[(size_t)(bm + t) * NCLUST + (bx >> 1)], s);
  }
}

// ---------------- softmax over 16 clusters per row ----------------
__global__ __launch_bounds__(256) void softmax_kernel(const float* __restrict__ s_accum,
                                                      float* __restrict__ out0) {
  int r = blockIdx.x * 256 + threadIdx.x;
  const float4* sp = (const float4*)(s_accum + (size_t)r * 16);
  float v[16];
#pragma unroll
  for (int i = 0; i < 4; i++) {
    float4 a = sp[i];
    v[i * 4 + 0] = a.x; v[i * 4 + 1] = a.y; v[i * 4 + 2] = a.z; v[i * 4 + 3] = a.w;
  }
  // logits = (s_scaled / 2^24) / TEMP ; eta*d cancels in softmax
  const float lsc = 5.9604644775390625e-7f;   // 10 / 2^24
  float mx = -1e30f;
#pragma unroll
  for (int i = 0; i < 16; i++) { v[i] *= lsc; mx = fmaxf(mx, v[i]); }
  float sum = 0.f;
#pragma unroll
  for (int i = 0; i < 16; i++) { v[i] = __expf(v[i] - mx); sum += v[i]; }
  float rs = 1.0f / sum;
  float4* op = (float4*)(out0 + (size_t)r * 16);
#pragma unroll
  for (int i = 0; i < 4; i++) {
    float4 a;
    a.x = v[i * 4 + 0] * rs; a.y = v[i * 4 + 1] * rs;
    a.z = v[i * 4 + 2] * rs; a.w = v[i * 4 + 3] * rs;
    op[i] = a;
  }
}

extern "C" void kernel_launch(void* const* d_in, const int* in_sizes, int n_in,
                              void* d_out, int out_size, void* d_ws, size_t ws_size,
                              hipStream_t stream) {
  const float* z = (const float*)d_in[0];
  const float* D = (const float*)d_in[1];
  float* out0 = (float*)d_out;
  float* out1 = out0 + (size_t)M_DIM * NCLUST;

  char* ws = (char*)d_ws;
  u8* zn   = (u8*)ws;                                                 // 64 MB
  u8* dnt  = (u8*)(ws + (size_t)M_DIM * K_DIM);                       // 16 MB
  float* colsq   = (float*)(ws + (size_t)M_DIM * K_DIM + (size_t)N_DIM * K_DIM);
  float* s_accum = colsq + N_DIM;                                     // contiguous

  const int nzero = N_DIM + M_DIM * NCLUST;   // colsq + s_accum (atomicAdd targets)
  zero_kernel<<<(nzero + 255) / 256, 256, 0, stream>>>(colsq, nzero);
  znorm_copy_kernel<<<M_DIM, 256, 0, stream>>>(z, out1, zn);
  colsq_kernel<<<dim3(N_DIM / 256, N_DIM / 128), 256, 0, stream>>>(D, colsq);
  dnt_kernel<<<dim3(N_DIM / 64, N_DIM / 64), 256, 0, stream>>>(D, colsq, dnt);
  gemm_kernel<<<(M_DIM / BM) * (N_DIM / BN), 512, 0, stream>>>(zn, dnt, s_accum);
  softmax_kernel<<<M_DIM / 256, 256, 0, stream>>>(s_accum, out0);
}

// Round 12
// 485.686 us; speedup vs baseline: 1.4377x; 1.4377x over previous
//
#include <hip/hip_runtime.h>

#define M_DIM 16384
#define N_DIM 4096
#define K_DIM 4096
#define NCLUST 16

#define BM 256
#define BN 128
#define BKB 128               // K-tile in BYTES per row (128 fp8 elements)
#define NT (K_DIM / BKB)      // 32 K-tiles

typedef unsigned short u16;
typedef unsigned char u8;
typedef float floatx4 __attribute__((ext_vector_type(4)));
typedef int int4v __attribute__((ext_vector_type(4)));
typedef int int8v __attribute__((ext_vector_type(8)));

typedef const unsigned int __attribute__((address_space(1))) gu32;
typedef unsigned int __attribute__((address_space(3))) lu32;

// float -> OCP e4m3fn with RNE (values are pre-scaled, |x| << 448)
__device__ __forceinline__ unsigned f2fp8(float x) {
  union { float f; unsigned u; } a; a.f = x;
  unsigned s = (a.u >> 24) & 0x80u;
  float ax = fabsf(x);
  if (ax >= 448.f) return s | 0x7Eu;
  if (ax < 0.015625f) {                       // subnormal: step 2^-9
    unsigned q = (unsigned)rintf(ax * 512.0f);
    return s | q;
  }
  unsigned u = a.u & 0x7FFFFFFFu;
  u += 0xFFFFFu + ((u >> 20) & 1u);           // RNE into 3-bit mantissa
  unsigned E = u >> 23;
  return s | (((E - 120u) << 3) & 0x78u) | ((u >> 20) & 7u);
}

// ---------------- zero scratch accumulators (colsq + s_accum) ----------------
__global__ __launch_bounds__(256) void zero_kernel(float* __restrict__ p, int n) {
  int i = blockIdx.x * 256 + threadIdx.x;
  if (i < n) p[i] = 0.f;
}

// ---------------- z row-normalize -> fp8 (x64), plus copy z -> out1 ----------------
__global__ __launch_bounds__(256) void znorm_copy_kernel(const float* __restrict__ z,
                                                         float* __restrict__ out1,
                                                         u8* __restrict__ zn) {
  const int row = blockIdx.x;
  const int t = threadIdx.x;
  const size_t base = (size_t)row * K_DIM;
  const float4* zr = (const float4*)(z + base);
  float4 v[4];
  float ss = 0.f;
#pragma unroll
  for (int i = 0; i < 4; i++) {
    v[i] = zr[t + i * 256];
    ss += v[i].x * v[i].x + v[i].y * v[i].y + v[i].z * v[i].z + v[i].w * v[i].w;
  }
#pragma unroll
  for (int m = 1; m <= 32; m <<= 1) ss += __shfl_xor(ss, m, 64);
  __shared__ float red[4];
  if ((t & 63) == 0) red[t >> 6] = ss;
  __syncthreads();
  float tot = red[0] + red[1] + red[2] + red[3];
  float sc = 64.0f / fmaxf(sqrtf(tot), 1e-8f);   // x64 scaling folded into normalize
  float4* o1 = (float4*)(out1 + base);
  unsigned* znr = (unsigned*)(zn + base);
#pragma unroll
  for (int i = 0; i < 4; i++) {
    o1[t + i * 256] = v[i];
    unsigned pk = f2fp8(v[i].x * sc) | (f2fp8(v[i].y * sc) << 8) |
                  (f2fp8(v[i].z * sc) << 16) | (f2fp8(v[i].w * sc) << 24);
    znr[t + i * 256] = pk;
  }
}

// ---------------- D column squared-norms ----------------
__global__ __launch_bounds__(256) void colsq_kernel(const float* __restrict__ D,
                                                    float* __restrict__ colsq) {
  const int col = blockIdx.x * 256 + threadIdx.x;
  const int r0 = blockIdx.y * 128;
  float ss = 0.f;
#pragma unroll 4
  for (int r = 0; r < 128; r++) {
    float d = D[(size_t)(r0 + r) * N_DIM + col];
    ss += d * d;
  }
  atomicAdd(&colsq[col], ss);
}

// ---------------- D col-normalize + transpose -> fp8 (x64) DnT[N][K] ----------------
__global__ __launch_bounds__(256) void dnt_kernel(const float* __restrict__ D,
                                                  const float* __restrict__ colsq,
                                                  u8* __restrict__ dnt) {
  __shared__ float tile[64][65];
  const int c0 = blockIdx.x * 64, r0 = blockIdx.y * 64;
  const int t = threadIdx.x;
  const int tr = t >> 4;
  const int tc = (t & 15) * 4;
#pragma unroll
  for (int i = 0; i < 4; i++) {
    int row = i * 16 + tr;
    float4 v = *(const float4*)(D + (size_t)(r0 + row) * N_DIM + c0 + tc);
    tile[row][tc + 0] = v.x; tile[row][tc + 1] = v.y;
    tile[row][tc + 2] = v.z; tile[row][tc + 3] = v.w;
  }
  __syncthreads();
#pragma unroll
  for (int i = 0; i < 4; i++) {
    int nl = i * 16 + tr;
    float sc = 64.0f / fmaxf(sqrtf(colsq[c0 + nl]), 1e-8f);
    unsigned pk = f2fp8(tile[tc + 0][nl] * sc) | (f2fp8(tile[tc + 1][nl] * sc) << 8) |
                  (f2fp8(tile[tc + 2][nl] * sc) << 16) | (f2fp8(tile[tc + 3][nl] * sc) << 24);
    *(unsigned*)(dnt + (size_t)(c0 + nl) * K_DIM + r0 + tc) = pk;
  }
}

// ---------------- GEMM: 256x128, fp8, single-barrier pipelined iters ----------------
// R12: same index/swizzle/staging math as R10/R11 (0 conflicts, refcheck'd);
// new schedule with ONE barrier per K-tile and in-place fragment refill:
//   {barrier; sched_barrier; STAGE(kt+2)->buf((kt+2)%3); issue af23(kt) reads;
//    MFMA MH0 (af01,bf from prev iter); MFMA MH1 (af23); vmcnt(6);
//    read bf,af01 of kt+1 from buf((kt+1)%3)}
// Fragments: ONE 64-reg set (af[4],bf[4]) refilled in place after last use —
// avoids R11's 128-reg double-set spill. 3 LDS buffers (144 KB) keep
// {read-cur, read-next, stage} disjoint; stage-depth-2 + entry barrier
// protects buffer reuse. ds_reads are plain loads (compiler-tracked lgkm).
__global__ __launch_bounds__(512, 1) void gemm_kernel(const u8* __restrict__ zn,
                                                      const u8* __restrict__ dnt,
                                                      float* __restrict__ s_accum) {
  __shared__ u8 ldsA[3 * BM * BKB];   // 3 x 32 KB  (rows: [MH0 0..127][MH1 128..255])
  __shared__ u8 ldsB[3 * BN * BKB];   // 3 x 16 KB -> 144 KB total

  const int t = threadIdx.x;
  const int w = t >> 6, l = t & 63;
  const int lr = l & 15, lk = l >> 4;

  // XCD swizzle: 2048 blocks, 256 contiguous work-ids per XCD
  const int bid = blockIdx.x;
  const int swz = (bid & 7) * 256 + (bid >> 3);
  const int bx = swz & 31, by = swz >> 5;
  const int bm = by * BM, bn = bx * BN;
  const int wm = (w >> 1) * 64, wn = (w & 1) * 64;

  // ---- staging source (perm-swizzled slot), per-lane base pointers ----
  const int y = (l & 7) ^ ((l >> 3) & 7);
  const int gs = ((y & 3) << 1) | (y >> 2);      // perm^{-1}(slot ^ row&7)
  const u8* pA1 = zn + (size_t)(bm + (w >> 2) * 64 + (w & 3) * 8 + (l >> 3)) * K_DIM + gs * 16;
  const u8* pB1 = dnt + (size_t)(bn + w * 8 + (l >> 3)) * K_DIM + gs * 16;

  // stage whole tile KT into A-buffer byte offset OA (B offset = OA>>1): 6 loads
#define STAGE(OA, KT) do { \
    const int _ob = (OA) >> 1; \
    __builtin_amdgcn_global_load_lds((gu32*)(pA1 + (size_t)(KT) * BKB), \
        (lu32*)&ldsA[(OA) + w * 1024], 16, 0, 0); \
    __builtin_amdgcn_global_load_lds((gu32*)(pA1 + (size_t)128 * K_DIM + (size_t)(KT) * BKB), \
        (lu32*)&ldsA[(OA) + 8192 + w * 1024], 16, 0, 0); \
    __builtin_amdgcn_global_load_lds((gu32*)(pA1 + (size_t)32 * K_DIM + (size_t)(KT) * BKB), \
        (lu32*)&ldsA[(OA) + 16384 + w * 1024], 16, 0, 0); \
    __builtin_amdgcn_global_load_lds((gu32*)(pA1 + (size_t)160 * K_DIM + (size_t)(KT) * BKB), \
        (lu32*)&ldsA[(OA) + 16384 + 8192 + w * 1024], 16, 0, 0); \
    __builtin_amdgcn_global_load_lds((gu32*)(pB1 + (size_t)(KT) * BKB), \
        (lu32*)&ldsB[_ob + w * 1024], 16, 0, 0); \
    __builtin_amdgcn_global_load_lds((gu32*)(pB1 + (size_t)64 * K_DIM + (size_t)(KT) * BKB), \
        (lu32*)&ldsB[_ob + 8192 + w * 1024], 16, 0, 0); \
  } while (0)

  // ---- ds_read fragment byte offsets: first slot = lk^(lr&7), pair at ^64 ----
  int aOff[4], bOff[4];
#pragma unroll
  for (int m = 0; m < 4; m++) {
    int lrow = (m >= 2 ? 128 : 0) + (w >> 1) * 32 + (m & 1) * 16 + lr;
    aOff[m] = lrow * BKB + ((lk ^ (lr & 7)) * 16);
  }
#pragma unroll
  for (int n = 0; n < 4; n++) {
    int lrow = wn + n * 16 + lr;
    bOff[n] = lrow * BKB + ((lk ^ (lr & 7)) * 16);
  }

  int8v af[4], bf[4];
  floatx4 acc[4][4] = {};

#define LDFRAG(F, base, off) do { \
    int4v* _h = (int4v*)&(F); \
    _h[0] = *(const int4v*)((base) + (off)); \
    _h[1] = *(const int4v*)((base) + ((off) ^ 64)); \
  } while (0)

  // load bf[0..3] + af[0..1] of a tile from buffer at A-offset OA
#define READ_NEXT(OA) do { \
    const u8* _ab = ldsA + (OA); \
    const u8* _bb = ldsB + ((OA) >> 1); \
    _Pragma("unroll") \
    for (int ni = 0; ni < 4; ni++) LDFRAG(bf[ni], _bb, bOff[ni]); \
    LDFRAG(af[0], _ab, aOff[0]); \
    LDFRAG(af[1], _ab, aOff[1]); \
  } while (0)

#define MFMA_H(M0) do { \
    __builtin_amdgcn_s_setprio(1); \
    _Pragma("unroll") \
    for (int mi = 0; mi < 2; mi++) \
      _Pragma("unroll") \
      for (int ni = 0; ni < 4; ni++) \
        acc[(M0) + mi][ni] = __builtin_amdgcn_mfma_scale_f32_16x16x128_f8f6f4( \
            af[(M0) + mi], bf[ni], acc[(M0) + mi][ni], 0, 0, 0, 127u, 0, 127u); \
    __builtin_amdgcn_s_setprio(0); \
  } while (0)

#define VM6 asm volatile("s_waitcnt vmcnt(6)" ::: "memory")
#define VM0 asm volatile("s_waitcnt vmcnt(0)" ::: "memory")

  // one pipelined K-tile: cur buf OC, next buf ON; STG stages kt+2, WT drains
#define ITER(OC, ON, STG, WT, NXT) do { \
    __builtin_amdgcn_s_barrier(); \
    __builtin_amdgcn_sched_barrier(0); \
    STG; \
    LDFRAG(af[2], ldsA + (OC), aOff[2]); \
    LDFRAG(af[3], ldsA + (OC), aOff[3]); \
    MFMA_H(0); \
    MFMA_H(2); \
    WT; \
    NXT; \
  } while (0)

#define O0 0
#define O1 32768
#define O2 65536

  // prologue: stage tiles 0,1 into bufs 0,1; land tile0; preload its frags
  STAGE(O0, 0); STAGE(O1, 1);
  VM6;
  __builtin_amdgcn_s_barrier();
  READ_NEXT(O0);

  for (int kt = 0; kt < NT - 2; kt += 3) {
    ITER(O0, O1, STAGE(O2, kt + 2), VM6, READ_NEXT(O1));
    ITER(O1, O2, STAGE(O0, kt + 3), VM6, READ_NEXT(O2));
    ITER(O2, O0, STAGE(O1, kt + 4), VM6, READ_NEXT(O0));
  }
  // kt = NT-2 (buf0): no stage; land tile NT-1; read its frags
  ITER(O0, O1, ((void)0), VM0, READ_NEXT(O1));
  // kt = NT-1 (buf1): compute only
  ITER(O1, O1, ((void)0), ((void)0), ((void)0));

#undef ITER
#undef O0
#undef O1
#undef O2
#undef VM6
#undef VM0
#undef MFMA_H
#undef READ_NEXT
#undef LDFRAG
#undef STAGE

  // ---- epilogue: per-row square-sum over this wave's 64 cols; 2 N-halves
  // reduce via LDS; one atomicAdd per row into the block's cluster.
  __syncthreads();
  float* red = (float*)ldsA;    // [256 rows][2 wave-cols]
#pragma unroll
  for (int m = 0; m < 4; m++) {
#pragma unroll
    for (int r = 0; r < 4; r++) {
      float v = 0.f;
#pragma unroll
      for (int n = 0; n < 4; n++) { float x = acc[m][n][r]; v += x * x; }
      v += __shfl_xor(v, 1, 64);
      v += __shfl_xor(v, 2, 64);
      v += __shfl_xor(v, 4, 64);
      v += __shfl_xor(v, 8, 64);
      if (lr == 0) {
        int lrow = wm + m * 16 + lk * 4 + r;   // 0..255
        red[lrow * 2 + (w & 1)] = v;
      }
    }
  }
  __syncthreads();
  if (t < 256) {
    float s = red[t * 2 + 0] + red[t * 2 + 1];
    atomicAdd(&s_accum[(size_t)(bm + t) * NCLUST + (bx >> 1)], s);
  }
}

// ---------------- softmax over 16 clusters per row ----------------
__global__ __launch_bounds__(256) void softmax_kernel(const float* __restrict__ s_accum,
                                                      float* __restrict__ out0) {
  int r = blockIdx.x * 256 + threadIdx.x;
  const float4* sp = (const float4*)(s_accum + (size_t)r * 16);
  float v[16];
#pragma unroll
  for (int i = 0; i < 4; i++) {
    float4 a = sp[i];
    v[i * 4 + 0] = a.x; v[i * 4 + 1] = a.y; v[i * 4 + 2] = a.z; v[i * 4 + 3] = a.w;
  }
  // logits = (s_scaled / 2^24) / TEMP ; eta*d cancels in softmax
  const float lsc = 5.9604644775390625e-7f;   // 10 / 2^24
  float mx = -1e30f;
#pragma unroll
  for (int i = 0; i < 16; i++) { v[i] *= lsc; mx = fmaxf(mx, v[i]); }
  float sum = 0.f;
#pragma unroll
  for (int i = 0; i < 16; i++) { v[i] = __expf(v[i] - mx); sum += v[i]; }
  float rs = 1.0f / sum;
  float4* op = (float4*)(out0 + (size_t)r * 16);
#pragma unroll
  for (int i = 0; i < 4; i++) {
    float4 a;
    a.x = v[i * 4 + 0] * rs; a.y = v[i * 4 + 1] * rs;
    a.z = v[i * 4 + 2] * rs; a.w = v[i * 4 + 3] * rs;
    op[i] = a;
  }
}

extern "C" void kernel_launch(void* const* d_in, const int* in_sizes, int n_in,
                              void* d_out, int out_size, void* d_ws, size_t ws_size,
                              hipStream_t stream) {
  const float* z = (const float*)d_in[0];
  const float* D = (const float*)d_in[1];
  float* out0 = (float*)d_out;
  float* out1 = out0 + (size_t)M_DIM * NCLUST;

  char* ws = (char*)d_ws;
  u8* zn   = (u8*)ws;                                                 // 64 MB
  u8* dnt  = (u8*)(ws + (size_t)M_DIM * K_DIM);                       // 16 MB
  float* colsq   = (float*)(ws + (size_t)M_DIM * K_DIM + (size_t)N_DIM * K_DIM);
  float* s_accum = colsq + N_DIM;                                     // contiguous

  const int nzero = N_DIM + M_DIM * NCLUST;   // colsq + s_accum (atomicAdd targets)
  zero_kernel<<<(nzero + 255) / 256, 256, 0, stream>>>(colsq, nzero);
  znorm_copy_kernel<<<M_DIM, 256, 0, stream>>>(z, out1, zn);
  colsq_kernel<<<dim3(N_DIM / 256, N_DIM / 128), 256, 0, stream>>>(D, colsq);
  dnt_kernel<<<dim3(N_DIM / 64, N_DIM / 64), 256, 0, stream>>>(D, colsq, dnt);
  gemm_kernel<<<(M_DIM / BM) * (N_DIM / BN), 512, 0, stream>>>(zn, dnt, s_accum);
  softmax_kernel<<<M_DIM / 256, 256, 0, stream>>>(s_accum, out0);
}